// Round 7
// baseline (279.510 us; speedup 1.0000x reference)
//
#include <hip/hip_runtime.h>
#include <hip/hip_fp16.h>

// GCN 2-layer GraphConv (norm='both'), fp32 in/out, fp16 intermediates.
// Round 13: SPLIT kBx -> kB_scatter + xw1.
//   Rationale: kB's 52KB staging LDS was charged to all 6446 fused blocks,
//   capping xw1 at 3 blocks/CU (19% occ). kB no longer has random global
//   atomics to hide (since r8), so fusion only throttles xw1. Standalone:
//   xw1 @20KB -> 8 blocks/CU; kB = 196 concurrent blocks (~1/CU).
//   kB / xw1 inner code byte-identical to round 12. kC / pulls unchanged.
//
// ws: int deg[N] | rowptr[N] | f32 in_norm[N] | out_norm[N] | int gcur[1024] |
//     int col[E] | f16 h1[64N] | f16 h2[32N]
//     binbuf_d[391*CAP ints] aliases h2+ (dead before pull64 writes h2);
//     binbuf_s[391*CAP bytes] follows.

#define BIN_SH 8
#define NBINS 391             // ceil(100000/256)
#define SRC_OFF 512
#define CAP 5120              // mean 4096 + 16 sigma
#define KB_EPT 32             // 8192 edges per kB block

// ---- kB_scatter: LDS-staged multisplit (round-10 proven form) ----
__global__ __launch_bounds__(256) void kB_scatter(
    const int* __restrict__ src, const int* __restrict__ dst,
    int* __restrict__ gcur, int* __restrict__ binbuf_d,
    unsigned char* __restrict__ binbuf_s, int E) {
  __shared__ __align__(16) char smem[53248];
  int* stage_d = (int*)smem;
  unsigned char* stage_s = (unsigned char*)(smem + 32768);
  int* cnt_d  = (int*)(smem + 40960);
  int* cnt_s  = (int*)(smem + 43008);
  int* scan_d = (int*)(smem + 45056);
  int* scan_s = (int*)(smem + 47104);
  int* base_d = (int*)(smem + 49152);
  int* base_s = (int*)(smem + 51200);
  int t = threadIdx.x;

  cnt_d[t] = 0; cnt_d[t + 256] = 0;
  cnt_s[t] = 0; cnt_s[t + 256] = 0;
  __syncthreads();
  int base = blockIdx.x * (256 * KB_EPT);
  // pass 1: count
#pragma unroll 4
  for (int i = 0; i < KB_EPT; i++) {
    int e = base + i * 256 + t;
    if (e < E) {
      atomicAdd(&cnt_d[dst[e] >> BIN_SH], 1);
      atomicAdd(&cnt_s[src[e] >> BIN_SH], 1);
    }
  }
  __syncthreads();
  // pass 2: block scan of 512-entry counts (pairwise + HS over 256)
  {
    int* tmp = stage_d;           // staging area is free right now
    int a0 = cnt_d[2 * t], a1 = cnt_d[2 * t + 1];
    int b0 = cnt_s[2 * t], b1 = cnt_s[2 * t + 1];
    tmp[t] = a0 + a1;
    tmp[256 + t] = b0 + b1;
    __syncthreads();
#pragma unroll
    for (int off = 1; off < 256; off <<= 1) {
      int va = (t >= off) ? tmp[t - off] : 0;
      int vb = (t >= off) ? tmp[256 + t - off] : 0;
      __syncthreads();
      tmp[t] += va;
      tmp[256 + t] += vb;
      __syncthreads();
    }
    int ea = tmp[t] - (a0 + a1);
    int eb = tmp[256 + t] - (b0 + b1);
    scan_d[2 * t] = ea; scan_d[2 * t + 1] = ea + a0;
    scan_s[2 * t] = eb; scan_s[2 * t + 1] = eb + b0;
    __syncthreads();
  }
  // pass 2b: reserve global segments; then reset cnt as place cursors
  for (int i = t; i < 512; i += 256) {
    int c = cnt_d[i];
    base_d[i] = c ? atomicAdd(&gcur[i], c) : 0;
    int cs = cnt_s[i];
    base_s[i] = cs ? atomicAdd(&gcur[SRC_OFF + i], cs) : 0;
  }
  __syncthreads();
  cnt_d[t] = 0; cnt_d[t + 256] = 0;
  cnt_s[t] = 0; cnt_s[t + 256] = 0;
  __syncthreads();
  // pass 3: scatter into LDS staging (re-read src/dst, L2-hot)
#pragma unroll 4
  for (int i = 0; i < KB_EPT; i++) {
    int e = base + i * 256 + t;
    if (e < E) {
      int d = dst[e], s = src[e];
      int bd = d >> BIN_SH;
      int rd = atomicAdd(&cnt_d[bd], 1);
      stage_d[scan_d[bd] + rd] = ((d & 255) << 17) | s;
      int bs = s >> BIN_SH;
      int rs = atomicAdd(&cnt_s[bs], 1);
      stage_s[scan_s[bs] + rs] = (unsigned char)(s & 255);
    }
  }
  __syncthreads();
  // pass 4: coalesced per-bin segment copy to global
  int wv = t >> 6, ln = t & 63;
  for (int b = wv; b < NBINS; b += 4) {
    int sd = scan_d[b], cd = scan_d[b + 1] - sd;
    int gd = b * CAP + base_d[b];
    for (int j = ln; j < cd; j += 64) binbuf_d[gd + j] = stage_d[sd + j];
    int ss = scan_s[b], cs = scan_s[b + 1] - ss;
    int gs = b * CAP + base_s[b];
    for (int j = ln; j < cs; j += 64) binbuf_s[gs + j] = stage_s[ss + j];
  }
}

// ---- xw1: h1 = x @ W1, 16 rows/block, broadcast-float4 inner loop ----
__global__ __launch_bounds__(256) void xw1(
    const float* __restrict__ x, const float* __restrict__ W,
    __half* __restrict__ h1, int n) {
  __shared__ float Ws[64 * 64];   // 16 KB
  __shared__ float xs[16 * 64];   // 4 KB
  int t = threadIdx.x;
#pragma unroll
  for (int i = 0; i < 16; i++) Ws[i * 256 + t] = W[i * 256 + t];
  int row0 = blockIdx.x * 16;
  {
    int r = t >> 4, k4 = t & 15;
    int row = row0 + r;
    float4 v = make_float4(0.f, 0.f, 0.f, 0.f);
    if (row < n) v = ((const float4*)x)[(size_t)row * 16 + k4];
    ((float4*)xs)[t] = v;
  }
  __syncthreads();
  int c = t & 63, rq = t >> 6;
  float acc[4] = {0.f, 0.f, 0.f, 0.f};
#pragma unroll 4
  for (int kq = 0; kq < 16; kq++) {
    float w0 = Ws[(4 * kq + 0) * 64 + c];
    float w1 = Ws[(4 * kq + 1) * 64 + c];
    float w2 = Ws[(4 * kq + 2) * 64 + c];
    float w3 = Ws[(4 * kq + 3) * 64 + c];
#pragma unroll
    for (int rr = 0; rr < 4; rr++) {
      const float4 xv = *(const float4*)&xs[(rq + rr * 4) * 64 + kq * 4];
      acc[rr] += xv.x * w0 + xv.y * w1 + xv.z * w2 + xv.w * w3;
    }
  }
#pragma unroll
  for (int rr = 0; rr < 4; rr++) {
    int row = row0 + rq + rr * 4;
    if (row < n) h1[(size_t)row * 64 + c] = __float2half(acc[rr]);
  }
}

// ---- kC: [0,NBINS) dst CSR build; [NBINS,2*NBINS) src count -> out_norm,
//          then prescale h1 rows by out_norm (in place, coalesced) ----
__global__ __launch_bounds__(256) void kC_build(
    const int* __restrict__ gcur, const int* __restrict__ binbuf_d,
    const unsigned char* __restrict__ binbuf_s,
    int* __restrict__ col, int* __restrict__ rowptr, int* __restrict__ deg,
    float* __restrict__ in_norm, float* __restrict__ out_norm,
    __half* __restrict__ h1, int n) {
  __shared__ int lcnt[256];
  __shared__ int lptr[256];
  __shared__ int red[256];
  int b = blockIdx.x;
  int t = threadIdx.x;
  if (b >= NBINS) {
    // src-bin byte count -> out_norm, then scale h1 rows of this bin
    int sb = b - NBINS;
    int cnt = gcur[SRC_OFF + sb];
    const unsigned int* p4 =
        (const unsigned int*)(binbuf_s + (size_t)sb * CAP);
    lcnt[t] = 0;
    __syncthreads();
    int cw = (cnt + 3) >> 2;
    for (int i = t; i < cw; i += 256) {
      unsigned int v = p4[i];
      int rem = cnt - i * 4;
      atomicAdd(&lcnt[v & 255], 1);
      if (rem > 1) atomicAdd(&lcnt[(v >> 8) & 255], 1);
      if (rem > 2) atomicAdd(&lcnt[(v >> 16) & 255], 1);
      if (rem > 3) atomicAdd(&lcnt[v >> 24], 1);
    }
    __syncthreads();
    int node0 = sb << BIN_SH;
    int node = node0 + t;
    float o = rsqrtf(fmaxf((float)lcnt[t], 1.0f));
    if (node < n) out_norm[node] = o;
    float* onn = (float*)lptr;
    onn[t] = o;
    __syncthreads();
    // scale h1 rows [node0, node0+256) by out_norm (coalesced uint4 stream)
    uint4* h1q = (uint4*)h1 + (size_t)node0 * 8;
#pragma unroll
    for (int i = 0; i < 8; i++) {
      int idx = i * 256 + t;            // uint4 index within bin
      int r = idx >> 3;                 // row within bin
      if (node0 + r < n) {
        float sc = onn[r];
        uint4 v = h1q[idx];
        __half2* hp = (__half2*)&v;
#pragma unroll
        for (int q = 0; q < 4; q++) {
          float2 f = __half22float2(hp[q]);
          f.x *= sc; f.y *= sc;
          hp[q] = __float22half2_rn(f);
        }
        h1q[idx] = v;
      }
    }
    return;
  }
  // compact col base = sum of dst-bin counts before b
  int part = 0;
  if (t < b) part = gcur[t];
  if (t + 256 < b) part += gcur[t + 256];
  red[t] = part;
  __syncthreads();
#pragma unroll
  for (int off = 128; off > 0; off >>= 1) {
    if (t < off) red[t] += red[t + off];
    __syncthreads();
  }
  int ebase = red[0];
  int cnt = gcur[b];
  const int* items = binbuf_d + (size_t)b * CAP;
  lcnt[t] = 0;
  __syncthreads();
  for (int i = t; i < cnt; i += 256) atomicAdd(&lcnt[items[i] >> 17], 1);
  __syncthreads();
  int cv = lcnt[t];
  lptr[t] = cv;
  __syncthreads();
#pragma unroll
  for (int off = 1; off < 256; off <<= 1) {
    int val = (t >= off) ? lptr[t - off] : 0;
    __syncthreads();
    lptr[t] += val;
    __syncthreads();
  }
  int ex = lptr[t] - cv;
  int node = (b << BIN_SH) + t;
  if (node < n) {
    rowptr[node] = ebase + ex;
    deg[node] = cv;
    in_norm[node] = rsqrtf(fmaxf((float)cv, 1.0f));
  }
  __syncthreads();
  lptr[t] = ex;
  __syncthreads();
  for (int i = t; i < cnt; i += 256) {
    int v = items[i];
    int r = atomicAdd(&lptr[v >> 17], 1);
    col[ebase + r] = v & 0x1FFFF;   // block-local region -> L2 merges
  }
}

__device__ inline void add8h(float* a, uint4 r) {
  const __half2* hp = reinterpret_cast<const __half2*>(&r);
#pragma unroll
  for (int i = 0; i < 4; i++) {
    float2 f = __half22float2(hp[i]);
    a[2 * i] += f.x;
    a[2 * i + 1] += f.y;
  }
}

// ---- pull64 + fused xw2 (h1 rows are pre-scaled by out_norm) ----
__global__ __launch_bounds__(256) void pull64_xw2(
    const int* __restrict__ rowptr, const int* __restrict__ deg,
    const int* __restrict__ col, const __half* __restrict__ h1,
    const float* __restrict__ out_norm, const float* __restrict__ in_norm,
    const float* __restrict__ b1, const float* __restrict__ W2,
    __half* __restrict__ h2, int n) {
  __shared__ float W2s[64 * 32];
  __shared__ float xrow[4][64];
  int t = threadIdx.x;
#pragma unroll
  for (int i = 0; i < 8; i++) W2s[i * 256 + t] = W2[i * 256 + t];

  int w = t >> 6;
  int node = blockIdx.x * 4 + w;
  int l = t & 63;
  int sub = l >> 3, fq = l & 7;

  if (node < n) {
    int beg = rowptr[node];
    int end = beg + deg[node];
    float a0[8] = {0, 0, 0, 0, 0, 0, 0, 0};
    float a1[8] = {0, 0, 0, 0, 0, 0, 0, 0};
    int j = beg;
    for (; j + 16 <= end; j += 16) {
      int s0 = col[j + sub];
      int s1 = col[j + 8 + sub];
      uint4 r0 = ((const uint4*)h1)[(size_t)s0 * 8 + fq];
      uint4 r1 = ((const uint4*)h1)[(size_t)s1 * 8 + fq];
      add8h(a0, r0);
      add8h(a1, r1);
    }
    for (; j < end; j += 8) {
      int jj = j + sub;
      if (jj < end) {
        int s = col[jj];
        uint4 r = ((const uint4*)h1)[(size_t)s * 8 + fq];
        add8h(a0, r);
      }
    }
    float acc[8];
#pragma unroll
    for (int i = 0; i < 8; i++) acc[i] = a0[i] + a1[i];
#pragma unroll
    for (int d = 8; d <= 32; d <<= 1) {
#pragma unroll
      for (int i = 0; i < 8; i++) acc[i] += __shfl_xor(acc[i], d);
    }
    if (sub == 0) {
      float innv = in_norm[node];
      float onnv = out_norm[node];
      float4 ba = ((const float4*)b1)[fq * 2];
      float4 bb = ((const float4*)b1)[fq * 2 + 1];
      float bv[8] = {ba.x, ba.y, ba.z, ba.w, bb.x, bb.y, bb.z, bb.w};
#pragma unroll
      for (int i = 0; i < 8; i++)
        xrow[w][fq * 8 + i] = fmaxf(acc[i] * innv + bv[i], 0.0f) * onnv;
    }
  }
  __syncthreads();
  if (t < 128) {
    int w2 = t >> 5, c = t & 31;
    int nd = blockIdx.x * 4 + w2;
    if (nd < n) {
      float dot = 0.f;
#pragma unroll 16
      for (int k = 0; k < 64; k++) dot += xrow[w2][k] * W2s[k * 32 + c];
      h2[(size_t)nd * 32 + c] = __float2half(dot);
    }
  }
}

// ---- pull 32 feats + epilogue ----
__global__ __launch_bounds__(256) void gcn_pull32(const int* __restrict__ rowptr,
                                                  const int* __restrict__ deg,
                                                  const int* __restrict__ col,
                                                  const __half* __restrict__ h,
                                                  const float* __restrict__ in_norm,
                                                  const float* __restrict__ b2,
                                                  float* __restrict__ out, int n) {
  int t = threadIdx.x;
  int node = blockIdx.x * 4 + (t >> 6);
  if (node >= n) return;
  int l = t & 63;
  int sub = l >> 3, fq = l & 7;
  int beg = rowptr[node];
  int end = beg + deg[node];
  float a0[4] = {0, 0, 0, 0}, a1[4] = {0, 0, 0, 0};
  int j = beg;
  for (; j + 16 <= end; j += 16) {
    int s0 = col[j + sub];
    int s1 = col[j + 8 + sub];
    uint2 r0 = ((const uint2*)h)[(size_t)s0 * 8 + fq];
    uint2 r1 = ((const uint2*)h)[(size_t)s1 * 8 + fq];
    const __half2* p0 = reinterpret_cast<const __half2*>(&r0);
    const __half2* p1 = reinterpret_cast<const __half2*>(&r1);
#pragma unroll
    for (int i = 0; i < 2; i++) {
      float2 f0 = __half22float2(p0[i]);
      float2 f1 = __half22float2(p1[i]);
      a0[2 * i] += f0.x; a0[2 * i + 1] += f0.y;
      a1[2 * i] += f1.x; a1[2 * i + 1] += f1.y;
    }
  }
  for (; j < end; j += 8) {
    int jj = j + sub;
    if (jj < end) {
      int s = col[jj];
      uint2 r = ((const uint2*)h)[(size_t)s * 8 + fq];
      const __half2* p = reinterpret_cast<const __half2*>(&r);
#pragma unroll
      for (int i = 0; i < 2; i++) {
        float2 f = __half22float2(p[i]);
        a0[2 * i] += f.x; a0[2 * i + 1] += f.y;
      }
    }
  }
  float acc[4];
#pragma unroll
  for (int i = 0; i < 4; i++) acc[i] = a0[i] + a1[i];
#pragma unroll
  for (int d = 8; d <= 32; d <<= 1) {
#pragma unroll
    for (int i = 0; i < 4; i++) acc[i] += __shfl_xor(acc[i], d);
  }
  if (sub == 0) {
    float s = in_norm[node];
    float4 bb = ((const float4*)b2)[fq];
    float4 o;
    o.x = acc[0] * s + bb.x;
    o.y = acc[1] * s + bb.y;
    o.z = acc[2] * s + bb.z;
    o.w = acc[3] * s + bb.w;
    ((float4*)out)[(size_t)node * 8 + fq] = o;
  }
}

extern "C" void kernel_launch(void* const* d_in, const int* in_sizes, int n_in,
                              void* d_out, int out_size, void* d_ws, size_t ws_size,
                              hipStream_t stream) {
  const float* x   = (const float*)d_in[0];
  const int*   src = (const int*)d_in[1];
  const int*   dst = (const int*)d_in[2];
  const float* W1  = (const float*)d_in[3];
  const float* b1  = (const float*)d_in[4];
  const float* W2  = (const float*)d_in[5];
  const float* b2  = (const float*)d_in[6];
  float* out = (float*)d_out;

  const int N = in_sizes[0] / 64;   // 100000
  const int E = in_sizes[1];        // 1600000

  int* deg        = (int*)d_ws;                // N
  int* rowptr     = deg + N;                   // N
  float* in_norm  = (float*)(rowptr + N);      // N
  float* out_norm = in_norm + N;               // N
  int* gcur       = (int*)(out_norm + N);      // 1024
  int* col        = gcur + 1024;               // E (compact)
  __half* h1 = (__half*)(col + E);             // 64N halves
  __half* h2 = h1 + (size_t)64 * N;            // 32N halves
  int* binbuf_d = (int*)h2;                    // 391*CAP ints (aliases h2+, dead later)
  unsigned char* binbuf_s =
      (unsigned char*)(binbuf_d + (size_t)NBINS * CAP);  // 391*CAP bytes

  hipMemsetAsync(gcur, 0, 1024 * sizeof(int), stream);

  const int NKB = (E + 256 * KB_EPT - 1) / (256 * KB_EPT);  // 196
  const int GX = (N + 15) / 16;                             // 6250
  kB_scatter<<<NKB, 256, 0, stream>>>(src, dst, gcur, binbuf_d, binbuf_s, E);
  xw1<<<GX, 256, 0, stream>>>(x, W1, h1, N);
  kC_build<<<2 * NBINS, 256, 0, stream>>>(gcur, binbuf_d, binbuf_s, col, rowptr,
                                          deg, in_norm, out_norm, h1, N);
  pull64_xw2<<<(N + 3) / 4, 256, 0, stream>>>(rowptr, deg, col, h1, out_norm,
                                              in_norm, b1, W2, h2, N);
  gcn_pull32<<<(N + 3) / 4, 256, 0, stream>>>(rowptr, deg, col, h2, in_norm, b2, out, N);
}

// Round 8
// 245.814 us; speedup vs baseline: 1.1371x; 1.1371x over previous
//
#include <hip/hip_runtime.h>
#include <hip/hip_fp16.h>

// GCN 2-layer GraphConv (norm='both'), fp32 in/out, fp16 intermediates.
// Round 14: kB_scatter -> 1024 threads/block (KB_EPT=8, same 8192 edges/block,
//   same 196 blocks, same 52KB LDS, same staging logic). r13 showed kB is
//   latency-bound at 4 waves/CU (occ 7.8%, VALU 8%, HBM 3%); 16 waves/block
//   quadruples latency hiding. Scan = masked HS over 1024 threads (two
//   independent 512-scans). xw1 / kC / pulls byte-identical to r13.
//
// ws: int deg[N] | rowptr[N] | f32 in_norm[N] | out_norm[N] | int gcur[1024] |
//     int col[E] | f16 h1[64N] | f16 h2[32N]
//     binbuf_d[391*CAP ints] aliases h2+ (dead before pull64 writes h2);
//     binbuf_s[391*CAP bytes] follows.

#define BIN_SH 8
#define NBINS 391             // ceil(100000/256)
#define SRC_OFF 512
#define CAP 5120              // mean 4096 + 16 sigma
#define KB_EPT 8              // 8192 edges per 1024-thread kB block

// ---- kB_scatter: LDS-staged multisplit, 1024 threads ----
__global__ __launch_bounds__(1024) void kB_scatter(
    const int* __restrict__ src, const int* __restrict__ dst,
    int* __restrict__ gcur, int* __restrict__ binbuf_d,
    unsigned char* __restrict__ binbuf_s, int E) {
  __shared__ __align__(16) char smem[53248];
  int* stage_d = (int*)smem;                         // 8192 ints (32 KB)
  unsigned char* stage_s = (unsigned char*)(smem + 32768);  // 8192 B
  int* cnt_d  = (int*)(smem + 40960);                // 512
  int* cnt_s  = (int*)(smem + 43008);                // 512
  int* scan_d = (int*)(smem + 45056);                // 512
  int* scan_s = (int*)(smem + 47104);                // 512
  int* base_d = (int*)(smem + 49152);                // 512
  int* base_s = (int*)(smem + 51200);                // 512
  int t = threadIdx.x;

  if (t < 512) { cnt_d[t] = 0; cnt_s[t] = 0; }
  __syncthreads();
  int base = blockIdx.x * (1024 * KB_EPT);
  // pass 1: count
#pragma unroll
  for (int i = 0; i < KB_EPT; i++) {
    int e = base + i * 1024 + t;
    if (e < E) {
      atomicAdd(&cnt_d[dst[e] >> BIN_SH], 1);
      atomicAdd(&cnt_s[src[e] >> BIN_SH], 1);
    }
  }
  __syncthreads();
  // pass 2: two independent 512-entry scans via masked HS over 1024 threads
  {
    int* tmp = stage_d;           // staging area free; need 1024 ints
    int v = (t < 512) ? cnt_d[t] : cnt_s[t - 512];
    tmp[t] = v;
    __syncthreads();
#pragma unroll
    for (int off = 1; off < 512; off <<= 1) {
      int val = ((t & 511) >= off) ? tmp[t - off] : 0;
      __syncthreads();
      tmp[t] += val;
      __syncthreads();
    }
    int ex = tmp[t] - v;
    if (t < 512) scan_d[t] = ex; else scan_s[t - 512] = ex;
    __syncthreads();
  }
  // pass 2b: reserve global segments; then reset cnt as place cursors
  if (t < 512) {
    int c = cnt_d[t];
    base_d[t] = c ? atomicAdd(&gcur[t], c) : 0;
  } else {
    int i = t - 512;
    int cs = cnt_s[i];
    base_s[i] = cs ? atomicAdd(&gcur[SRC_OFF + i], cs) : 0;
  }
  __syncthreads();
  if (t < 512) { cnt_d[t] = 0; cnt_s[t] = 0; }
  __syncthreads();
  // pass 3: scatter into LDS staging (re-read src/dst, L2-hot)
#pragma unroll
  for (int i = 0; i < KB_EPT; i++) {
    int e = base + i * 1024 + t;
    if (e < E) {
      int d = dst[e], s = src[e];
      int bd = d >> BIN_SH;
      int rd = atomicAdd(&cnt_d[bd], 1);
      stage_d[scan_d[bd] + rd] = ((d & 255) << 17) | s;
      int bs = s >> BIN_SH;
      int rs = atomicAdd(&cnt_s[bs], 1);
      stage_s[scan_s[bs] + rs] = (unsigned char)(s & 255);
    }
  }
  __syncthreads();
  // pass 4: coalesced per-bin segment copy to global (16 waves)
  int wv = t >> 6, ln = t & 63;
  for (int b = wv; b < NBINS; b += 16) {
    int sd = scan_d[b];
    int cd = ((b + 1 < 512) ? ((b + 1 == 512) ? 8192 : scan_d[b + 1]) : 8192) - sd;
    // note: scan_d[b+1] valid for b+1<512; bin 511 unused (NBINS=391)
    cd = scan_d[b + 1] - sd;
    int gd = b * CAP + base_d[b];
    for (int j = ln; j < cd; j += 64) binbuf_d[gd + j] = stage_d[sd + j];
    int ss = scan_s[b], cs = scan_s[b + 1] - ss;
    int gs = b * CAP + base_s[b];
    for (int j = ln; j < cs; j += 64) binbuf_s[gs + j] = stage_s[ss + j];
  }
}

// ---- xw1: h1 = x @ W1, 16 rows/block, broadcast-float4 inner loop ----
__global__ __launch_bounds__(256) void xw1(
    const float* __restrict__ x, const float* __restrict__ W,
    __half* __restrict__ h1, int n) {
  __shared__ float Ws[64 * 64];   // 16 KB
  __shared__ float xs[16 * 64];   // 4 KB
  int t = threadIdx.x;
#pragma unroll
  for (int i = 0; i < 16; i++) Ws[i * 256 + t] = W[i * 256 + t];
  int row0 = blockIdx.x * 16;
  {
    int r = t >> 4, k4 = t & 15;
    int row = row0 + r;
    float4 v = make_float4(0.f, 0.f, 0.f, 0.f);
    if (row < n) v = ((const float4*)x)[(size_t)row * 16 + k4];
    ((float4*)xs)[t] = v;
  }
  __syncthreads();
  int c = t & 63, rq = t >> 6;
  float acc[4] = {0.f, 0.f, 0.f, 0.f};
#pragma unroll 4
  for (int kq = 0; kq < 16; kq++) {
    float w0 = Ws[(4 * kq + 0) * 64 + c];
    float w1 = Ws[(4 * kq + 1) * 64 + c];
    float w2 = Ws[(4 * kq + 2) * 64 + c];
    float w3 = Ws[(4 * kq + 3) * 64 + c];
#pragma unroll
    for (int rr = 0; rr < 4; rr++) {
      const float4 xv = *(const float4*)&xs[(rq + rr * 4) * 64 + kq * 4];
      acc[rr] += xv.x * w0 + xv.y * w1 + xv.z * w2 + xv.w * w3;
    }
  }
#pragma unroll
  for (int rr = 0; rr < 4; rr++) {
    int row = row0 + rq + rr * 4;
    if (row < n) h1[(size_t)row * 64 + c] = __float2half(acc[rr]);
  }
}

// ---- kC: [0,NBINS) dst CSR build; [NBINS,2*NBINS) src count -> out_norm,
//          then prescale h1 rows by out_norm (in place, coalesced) ----
__global__ __launch_bounds__(256) void kC_build(
    const int* __restrict__ gcur, const int* __restrict__ binbuf_d,
    const unsigned char* __restrict__ binbuf_s,
    int* __restrict__ col, int* __restrict__ rowptr, int* __restrict__ deg,
    float* __restrict__ in_norm, float* __restrict__ out_norm,
    __half* __restrict__ h1, int n) {
  __shared__ int lcnt[256];
  __shared__ int lptr[256];
  __shared__ int red[256];
  int b = blockIdx.x;
  int t = threadIdx.x;
  if (b >= NBINS) {
    // src-bin byte count -> out_norm, then scale h1 rows of this bin
    int sb = b - NBINS;
    int cnt = gcur[SRC_OFF + sb];
    const unsigned int* p4 =
        (const unsigned int*)(binbuf_s + (size_t)sb * CAP);
    lcnt[t] = 0;
    __syncthreads();
    int cw = (cnt + 3) >> 2;
    for (int i = t; i < cw; i += 256) {
      unsigned int v = p4[i];
      int rem = cnt - i * 4;
      atomicAdd(&lcnt[v & 255], 1);
      if (rem > 1) atomicAdd(&lcnt[(v >> 8) & 255], 1);
      if (rem > 2) atomicAdd(&lcnt[(v >> 16) & 255], 1);
      if (rem > 3) atomicAdd(&lcnt[v >> 24], 1);
    }
    __syncthreads();
    int node0 = sb << BIN_SH;
    int node = node0 + t;
    float o = rsqrtf(fmaxf((float)lcnt[t], 1.0f));
    if (node < n) out_norm[node] = o;
    float* onn = (float*)lptr;
    onn[t] = o;
    __syncthreads();
    // scale h1 rows [node0, node0+256) by out_norm (coalesced uint4 stream)
    uint4* h1q = (uint4*)h1 + (size_t)node0 * 8;
#pragma unroll
    for (int i = 0; i < 8; i++) {
      int idx = i * 256 + t;            // uint4 index within bin
      int r = idx >> 3;                 // row within bin
      if (node0 + r < n) {
        float sc = onn[r];
        uint4 v = h1q[idx];
        __half2* hp = (__half2*)&v;
#pragma unroll
        for (int q = 0; q < 4; q++) {
          float2 f = __half22float2(hp[q]);
          f.x *= sc; f.y *= sc;
          hp[q] = __float22half2_rn(f);
        }
        h1q[idx] = v;
      }
    }
    return;
  }
  // compact col base = sum of dst-bin counts before b
  int part = 0;
  if (t < b) part = gcur[t];
  if (t + 256 < b) part += gcur[t + 256];
  red[t] = part;
  __syncthreads();
#pragma unroll
  for (int off = 128; off > 0; off >>= 1) {
    if (t < off) red[t] += red[t + off];
    __syncthreads();
  }
  int ebase = red[0];
  int cnt = gcur[b];
  const int* items = binbuf_d + (size_t)b * CAP;
  lcnt[t] = 0;
  __syncthreads();
  for (int i = t; i < cnt; i += 256) atomicAdd(&lcnt[items[i] >> 17], 1);
  __syncthreads();
  int cv = lcnt[t];
  lptr[t] = cv;
  __syncthreads();
#pragma unroll
  for (int off = 1; off < 256; off <<= 1) {
    int val = (t >= off) ? lptr[t - off] : 0;
    __syncthreads();
    lptr[t] += val;
    __syncthreads();
  }
  int ex = lptr[t] - cv;
  int node = (b << BIN_SH) + t;
  if (node < n) {
    rowptr[node] = ebase + ex;
    deg[node] = cv;
    in_norm[node] = rsqrtf(fmaxf((float)cv, 1.0f));
  }
  __syncthreads();
  lptr[t] = ex;
  __syncthreads();
  for (int i = t; i < cnt; i += 256) {
    int v = items[i];
    int r = atomicAdd(&lptr[v >> 17], 1);
    col[ebase + r] = v & 0x1FFFF;   // block-local region -> L2 merges
  }
}

__device__ inline void add8h(float* a, uint4 r) {
  const __half2* hp = reinterpret_cast<const __half2*>(&r);
#pragma unroll
  for (int i = 0; i < 4; i++) {
    float2 f = __half22float2(hp[i]);
    a[2 * i] += f.x;
    a[2 * i + 1] += f.y;
  }
}

// ---- pull64 + fused xw2 (h1 rows are pre-scaled by out_norm) ----
__global__ __launch_bounds__(256) void pull64_xw2(
    const int* __restrict__ rowptr, const int* __restrict__ deg,
    const int* __restrict__ col, const __half* __restrict__ h1,
    const float* __restrict__ out_norm, const float* __restrict__ in_norm,
    const float* __restrict__ b1, const float* __restrict__ W2,
    __half* __restrict__ h2, int n) {
  __shared__ float W2s[64 * 32];
  __shared__ float xrow[4][64];
  int t = threadIdx.x;
#pragma unroll
  for (int i = 0; i < 8; i++) W2s[i * 256 + t] = W2[i * 256 + t];

  int w = t >> 6;
  int node = blockIdx.x * 4 + w;
  int l = t & 63;
  int sub = l >> 3, fq = l & 7;

  if (node < n) {
    int beg = rowptr[node];
    int end = beg + deg[node];
    float a0[8] = {0, 0, 0, 0, 0, 0, 0, 0};
    float a1[8] = {0, 0, 0, 0, 0, 0, 0, 0};
    int j = beg;
    for (; j + 16 <= end; j += 16) {
      int s0 = col[j + sub];
      int s1 = col[j + 8 + sub];
      uint4 r0 = ((const uint4*)h1)[(size_t)s0 * 8 + fq];
      uint4 r1 = ((const uint4*)h1)[(size_t)s1 * 8 + fq];
      add8h(a0, r0);
      add8h(a1, r1);
    }
    for (; j < end; j += 8) {
      int jj = j + sub;
      if (jj < end) {
        int s = col[jj];
        uint4 r = ((const uint4*)h1)[(size_t)s * 8 + fq];
        add8h(a0, r);
      }
    }
    float acc[8];
#pragma unroll
    for (int i = 0; i < 8; i++) acc[i] = a0[i] + a1[i];
#pragma unroll
    for (int d = 8; d <= 32; d <<= 1) {
#pragma unroll
      for (int i = 0; i < 8; i++) acc[i] += __shfl_xor(acc[i], d);
    }
    if (sub == 0) {
      float innv = in_norm[node];
      float onnv = out_norm[node];
      float4 ba = ((const float4*)b1)[fq * 2];
      float4 bb = ((const float4*)b1)[fq * 2 + 1];
      float bv[8] = {ba.x, ba.y, ba.z, ba.w, bb.x, bb.y, bb.z, bb.w};
#pragma unroll
      for (int i = 0; i < 8; i++)
        xrow[w][fq * 8 + i] = fmaxf(acc[i] * innv + bv[i], 0.0f) * onnv;
    }
  }
  __syncthreads();
  if (t < 128) {
    int w2 = t >> 5, c = t & 31;
    int nd = blockIdx.x * 4 + w2;
    if (nd < n) {
      float dot = 0.f;
#pragma unroll 16
      for (int k = 0; k < 64; k++) dot += xrow[w2][k] * W2s[k * 32 + c];
      h2[(size_t)nd * 32 + c] = __float2half(dot);
    }
  }
}

// ---- pull 32 feats + epilogue ----
__global__ __launch_bounds__(256) void gcn_pull32(const int* __restrict__ rowptr,
                                                  const int* __restrict__ deg,
                                                  const int* __restrict__ col,
                                                  const __half* __restrict__ h,
                                                  const float* __restrict__ in_norm,
                                                  const float* __restrict__ b2,
                                                  float* __restrict__ out, int n) {
  int t = threadIdx.x;
  int node = blockIdx.x * 4 + (t >> 6);
  if (node >= n) return;
  int l = t & 63;
  int sub = l >> 3, fq = l & 7;
  int beg = rowptr[node];
  int end = beg + deg[node];
  float a0[4] = {0, 0, 0, 0}, a1[4] = {0, 0, 0, 0};
  int j = beg;
  for (; j + 16 <= end; j += 16) {
    int s0 = col[j + sub];
    int s1 = col[j + 8 + sub];
    uint2 r0 = ((const uint2*)h)[(size_t)s0 * 8 + fq];
    uint2 r1 = ((const uint2*)h)[(size_t)s1 * 8 + fq];
    const __half2* p0 = reinterpret_cast<const __half2*>(&r0);
    const __half2* p1 = reinterpret_cast<const __half2*>(&r1);
#pragma unroll
    for (int i = 0; i < 2; i++) {
      float2 f0 = __half22float2(p0[i]);
      float2 f1 = __half22float2(p1[i]);
      a0[2 * i] += f0.x; a0[2 * i + 1] += f0.y;
      a1[2 * i] += f1.x; a1[2 * i + 1] += f1.y;
    }
  }
  for (; j < end; j += 8) {
    int jj = j + sub;
    if (jj < end) {
      int s = col[jj];
      uint2 r = ((const uint2*)h)[(size_t)s * 8 + fq];
      const __half2* p = reinterpret_cast<const __half2*>(&r);
#pragma unroll
      for (int i = 0; i < 2; i++) {
        float2 f = __half22float2(p[i]);
        a0[2 * i] += f.x; a0[2 * i + 1] += f.y;
      }
    }
  }
  float acc[4];
#pragma unroll
  for (int i = 0; i < 4; i++) acc[i] = a0[i] + a1[i];
#pragma unroll
  for (int d = 8; d <= 32; d <<= 1) {
#pragma unroll
    for (int i = 0; i < 4; i++) acc[i] += __shfl_xor(acc[i], d);
  }
  if (sub == 0) {
    float s = in_norm[node];
    float4 bb = ((const float4*)b2)[fq];
    float4 o;
    o.x = acc[0] * s + bb.x;
    o.y = acc[1] * s + bb.y;
    o.z = acc[2] * s + bb.z;
    o.w = acc[3] * s + bb.w;
    ((float4*)out)[(size_t)node * 8 + fq] = o;
  }
}

extern "C" void kernel_launch(void* const* d_in, const int* in_sizes, int n_in,
                              void* d_out, int out_size, void* d_ws, size_t ws_size,
                              hipStream_t stream) {
  const float* x   = (const float*)d_in[0];
  const int*   src = (const int*)d_in[1];
  const int*   dst = (const int*)d_in[2];
  const float* W1  = (const float*)d_in[3];
  const float* b1  = (const float*)d_in[4];
  const float* W2  = (const float*)d_in[5];
  const float* b2  = (const float*)d_in[6];
  float* out = (float*)d_out;

  const int N = in_sizes[0] / 64;   // 100000
  const int E = in_sizes[1];        // 1600000

  int* deg        = (int*)d_ws;                // N
  int* rowptr     = deg + N;                   // N
  float* in_norm  = (float*)(rowptr + N);      // N
  float* out_norm = in_norm + N;               // N
  int* gcur       = (int*)(out_norm + N);      // 1024
  int* col        = gcur + 1024;               // E (compact)
  __half* h1 = (__half*)(col + E);             // 64N halves
  __half* h2 = h1 + (size_t)64 * N;            // 32N halves
  int* binbuf_d = (int*)h2;                    // 391*CAP ints (aliases h2+, dead later)
  unsigned char* binbuf_s =
      (unsigned char*)(binbuf_d + (size_t)NBINS * CAP);  // 391*CAP bytes

  hipMemsetAsync(gcur, 0, 1024 * sizeof(int), stream);

  const int NKB = (E + 1024 * KB_EPT - 1) / (1024 * KB_EPT);  // 196
  const int GX = (N + 15) / 16;                               // 6250
  kB_scatter<<<NKB, 1024, 0, stream>>>(src, dst, gcur, binbuf_d, binbuf_s, E);
  xw1<<<GX, 256, 0, stream>>>(x, W1, h1, N);
  kC_build<<<2 * NBINS, 256, 0, stream>>>(gcur, binbuf_d, binbuf_s, col, rowptr,
                                          deg, in_norm, out_norm, h1, N);
  pull64_xw2<<<(N + 3) / 4, 256, 0, stream>>>(rowptr, deg, col, h1, out_norm,
                                              in_norm, b1, W2, h2, N);
  gcn_pull32<<<(N + 3) / 4, 256, 0, stream>>>(rowptr, deg, col, h2, in_norm, b2, out, N);
}